// Round 1
// baseline (10536.310 us; speedup 1.0000x reference)
//
#include <hip/hip_runtime.h>
#include <hip/hip_bf16.h>

// Problem constants (from reference)
#define BB   4
#define HH   256
#define WW   256
#define INCH 128
#define MIDC 64
#define NPAT 4      // patches per side
#define PP   16     // NPAT*NPAT
#define PS   64     // patch size (H/NPAT)

// ---------------------------------------------------------------------------
// Generic 3x3 same-pad conv + bias + ReLU (+ optional post-ReLU residual).
// Two-source input: channels [0,CSPLIT) from inA, [CSPLIT,CIN) from inB
// (used to fuse the concat for the final conv). inB may equal inA.
// Block: 256 threads -> 32x8 output tile, COPT output channels per thread.
// ---------------------------------------------------------------------------
template<int CIN, int COPT, int CSPLIT>
__global__ __launch_bounds__(256) void conv3x3_kernel(
    const float* __restrict__ inA,
    const float* __restrict__ inB,
    const float* __restrict__ wgt,   // [COUT, CIN, 3, 3]
    const float* __restrict__ bias,  // [COUT]
    const float* __restrict__ res,   // nullable, [B, COUT, H, W], added AFTER relu
    float* __restrict__ out,         // [B, COUT, H, W]
    int COUT)
{
    constexpr int HT = 8, WT = 32, CCH = 8;
    __shared__ float sm[CCH][HT + 2][WT + 2];

    const int tile = blockIdx.x;          // 8 tiles in x, 32 in y
    const int ty0 = (tile >> 3) * HT;
    const int tx0 = (tile & 7) * WT;
    const int cog = blockIdx.y * COPT;
    const int b   = blockIdx.z;
    const int t   = threadIdx.x;
    const int lx  = t & 31;
    const int ly  = t >> 5;               // 0..7

    float acc[COPT];
#pragma unroll
    for (int i = 0; i < COPT; ++i) acc[i] = bias[cog + i];

    for (int cb = 0; cb < CIN; cb += CCH) {
        __syncthreads();
        // stage CCH input slices (with halo) into LDS
        for (int idx = t; idx < CCH * (HT + 2) * (WT + 2); idx += 256) {
            int ci  = idx / ((HT + 2) * (WT + 2));
            int rem = idx - ci * ((HT + 2) * (WT + 2));
            int iy  = rem / (WT + 2);
            int ix  = rem - iy * (WT + 2);
            int gy  = ty0 + iy - 1;
            int gx  = tx0 + ix - 1;
            int c   = cb + ci;
            float v = 0.f;
            if ((unsigned)gy < (unsigned)HH && (unsigned)gx < (unsigned)WW) {
                if (c < CSPLIT)
                    v = inA[((size_t)(b * CSPLIT + c) * HH + gy) * WW + gx];
                else
                    v = inB[((size_t)(b * (CIN - CSPLIT) + (c - CSPLIT)) * HH + gy) * WW + gx];
            }
            sm[ci][iy][ix] = v;
        }
        __syncthreads();

#pragma unroll
        for (int ci = 0; ci < CCH; ++ci) {
            float v[3][3];
#pragma unroll
            for (int ky = 0; ky < 3; ++ky)
#pragma unroll
                for (int kx = 0; kx < 3; ++kx)
                    v[ky][kx] = sm[ci][ly + ky][lx + kx];

            const float* wp = wgt + ((size_t)cog * CIN + (cb + ci)) * 9;
#pragma unroll
            for (int co = 0; co < COPT; ++co) {
                const float* wc = wp + (size_t)co * CIN * 9;
#pragma unroll
                for (int k = 0; k < 9; ++k)
                    acc[co] = fmaf(v[k / 3][k % 3], wc[k], acc[co]);
            }
        }
    }

    const int oy = ty0 + ly;
    const int ox = tx0 + lx;
#pragma unroll
    for (int co = 0; co < COPT; ++co) {
        float o = fmaxf(acc[co], 0.f);
        size_t oi = ((size_t)(b * COUT + cog + co) * HH + oy) * WW + ox;
        if (res) o += res[oi];
        out[oi] = o;
    }
}

// ---------------------------------------------------------------------------
// transpose per-patch 1x1 weights [p][d][c] -> [p][c][d] for contiguous rows
// ---------------------------------------------------------------------------
__global__ __launch_bounds__(256) void transpose_pw_kernel(
    const float* __restrict__ w, float* __restrict__ wt)
{
    int idx = blockIdx.x * 256 + threadIdx.x;    // 16*64*64 = 65536
    int p = idx >> 12, d = (idx >> 6) & 63, c = idx & 63;
    wt[((size_t)(p * 64 + c)) * 64 + d] = w[idx];
}

// ---------------------------------------------------------------------------
// per-patch 1x1 conv: out[b,d,y,x] = bias[p,d] + sum_c wt[p,c,d] * in[b,c,y,x]
// block: 256 thr = 64x4 pixel tile (single patch), 16 d per thread (grid.y=4)
// ---------------------------------------------------------------------------
__global__ __launch_bounds__(256) void patch1x1_kernel(
    const float* __restrict__ in,    // [B,64,H,W]
    const float* __restrict__ wt,    // [16,64,64] (p,c,d)
    const float* __restrict__ bias,  // [16,64]
    float* __restrict__ out)         // [B,64,H,W]
{
    const int tile = blockIdx.x;     // tilesX = W/64 = 4, tilesY = H/4 = 64
    const int y0 = (tile >> 2) * 4;
    const int x0 = (tile & 3) * 64;
    const int dg = blockIdx.y * 16;
    const int b  = blockIdx.z;
    const int t  = threadIdx.x;
    const int lx = t & 63, ly = t >> 6;
    const int y = y0 + ly, x = x0 + lx;
    const int p = (y >> 6) * NPAT + (x >> 6);

    float acc[16];
#pragma unroll
    for (int d = 0; d < 16; ++d) acc[d] = bias[p * 64 + dg + d];

    const float* wp = wt + (size_t)(p * 64) * 64 + dg;
    const float* ip = in + ((size_t)(b * 64) * HH + y) * WW + x;
    for (int c = 0; c < 64; ++c) {
        float v = ip[(size_t)c * HH * WW];
        const float* wc = wp + c * 64;
#pragma unroll
        for (int d = 0; d < 16; ++d) acc[d] = fmaf(v, wc[d], acc[d]);
    }
#pragma unroll
    for (int d = 0; d < 16; ++d)
        out[((size_t)(b * 64 + dg + d) * HH + y) * WW + x] = acc[d];
}

// ---------------------------------------------------------------------------
// per-patch squared norm: outN[b*16+p] = sum over (c, patch pixels) of f^2
// ---------------------------------------------------------------------------
__global__ __launch_bounds__(256) void patch_norm_kernel(
    const float* __restrict__ f, float* __restrict__ outN)
{
    const int bp = blockIdx.x;
    const int b = bp >> 4, p = bp & 15;
    const int py = (p >> 2) * PS, px = (p & 3) * PS;
    const float* base = f + (size_t)(b * 64) * HH * WW;
    float s = 0.f;
    for (int idx = threadIdx.x; idx < 64 * PS * PS; idx += 256) {
        int c = idx >> 12, rem = idx & 4095;
        int i = rem >> 6, j = rem & 63;
        float v = base[((size_t)c * HH + py + i) * WW + px + j];
        s = fmaf(v, v, s);
    }
    __shared__ float red[256];
    red[threadIdx.x] = s; __syncthreads();
    for (int off = 128; off > 0; off >>= 1) {
        if (threadIdx.x < off) red[threadIdx.x] += red[threadIdx.x + off];
        __syncthreads();
    }
    if (threadIdx.x == 0) outN[bp] = red[0];
}

// ---------------------------------------------------------------------------
// pairwise patch dot products: dot[b*256 + p*16 + q] = f1[b,p] . f2[b,q]
// ---------------------------------------------------------------------------
__global__ __launch_bounds__(256) void patch_dot_kernel(
    const float* __restrict__ f1, const float* __restrict__ f2,
    float* __restrict__ dotv)
{
    const int id = blockIdx.x;
    const int b = id >> 8, p = (id >> 4) & 15, q = id & 15;
    const int py = (p >> 2) * PS, px = (p & 3) * PS;
    const int qy = (q >> 2) * PS, qx = (q & 3) * PS;
    const float* b1 = f1 + (size_t)(b * 64) * HH * WW;
    const float* b2 = f2 + (size_t)(b * 64) * HH * WW;
    float s = 0.f;
    for (int idx = threadIdx.x; idx < 64 * PS * PS; idx += 256) {
        int c = idx >> 12, rem = idx & 4095;
        int i = rem >> 6, j = rem & 63;
        s = fmaf(b1[((size_t)c * HH + py + i) * WW + px + j],
                 b2[((size_t)c * HH + qy + i) * WW + qx + j], s);
    }
    __shared__ float red[256];
    red[threadIdx.x] = s; __syncthreads();
    for (int off = 128; off > 0; off >>= 1) {
        if (threadIdx.x < off) red[threadIdx.x] += red[threadIdx.x + off];
        __syncthreads();
    }
    if (threadIdx.x == 0) dotv[id] = red[0];
}

// ---------------------------------------------------------------------------
// d = n1[p] + n2[q] - 2 dot[p,q]; diag -> 1e8; attn = softmax(exp(-d), q)
// one block, 1024 threads = all (b,p,q)
// ---------------------------------------------------------------------------
__global__ __launch_bounds__(1024) void attn_kernel(
    const float* __restrict__ n1, const float* __restrict__ n2,
    const float* __restrict__ dotv, float* __restrict__ attn)
{
    __shared__ float tv[1024];
    int t = threadIdx.x;
    int b = t >> 8, p = (t >> 4) & 15, q = t & 15;
    float d = n1[b * 16 + p] + n2[b * 16 + q] - 2.f * dotv[t];
    if (p == q) d = 1e8f;
    float e = expf(-d);
    tv[t] = e;
    __syncthreads();
    const float* row = &tv[(t >> 4) << 4];
    float m = row[0];
#pragma unroll
    for (int j = 1; j < 16; ++j) m = fmaxf(m, row[j]);
    float ssum = 0.f;
#pragma unroll
    for (int j = 0; j < 16; ++j) ssum += expf(row[j] - m);
    attn[t] = expf(e - m) / ssum;
}

// ---------------------------------------------------------------------------
// attention combine: outA[b,c,y,x] = sum_q attn[b,p(y,x),q] * x2p[b,c, q-pixel]
// ---------------------------------------------------------------------------
__global__ __launch_bounds__(256) void combine_kernel(
    const float* __restrict__ attn, const float* __restrict__ x2p,
    float* __restrict__ outA)
{
    const int tile = blockIdx.x;     // 64x4 pixel tile, same patch
    const int y0 = (tile >> 2) * 4;
    const int x0 = (tile & 3) * 64;
    const int c = blockIdx.y, b = blockIdx.z;
    const int t = threadIdx.x;
    const int lx = t & 63, ly = t >> 6;
    const int y = y0 + ly, x = x0 + lx;
    const int p = (y >> 6) * NPAT + (x >> 6);
    const int i = y & 63, j = x & 63;
    const float* arow = attn + (size_t)(b * 16 + p) * 16;
    const float* base = x2p + (size_t)(b * 64 + c) * HH * WW;
    float s = 0.f;
#pragma unroll
    for (int q = 0; q < 16; ++q) {
        s = fmaf(arow[q], base[(size_t)((q >> 2) * PS + i) * WW + (q & 3) * PS + j], s);
    }
    outA[((size_t)(b * 64 + c) * HH + y) * WW + x] = s;
}

// ---------------------------------------------------------------------------
extern "C" void kernel_launch(void* const* d_in, const int* in_sizes, int n_in,
                              void* d_out, int out_size, void* d_ws, size_t ws_size,
                              hipStream_t stream)
{
    const float* x     = (const float*)d_in[0];
    const float* pre_w = (const float*)d_in[1];
    const float* pre_b = (const float*)d_in[2];
    const float* c1_w  = (const float*)d_in[3];
    const float* c1_b  = (const float*)d_in[4];
    const float* c2_w  = (const float*)d_in[5];
    const float* c2_b  = (const float*)d_in[6];
    const float* p1_w  = (const float*)d_in[7];
    const float* p1_b  = (const float*)d_in[8];
    const float* p2_w  = (const float*)d_in[9];
    const float* p2_b  = (const float*)d_in[10];
    const float* fin_w = (const float*)d_in[11];
    const float* fin_b = (const float*)d_in[12];

    float* out = (float*)d_out;
    float* ws  = (float*)d_ws;

    const size_t sizeN = (size_t)BB * MIDC * HH * WW;   // 16,777,216 floats
    float* x0  = ws;                 // [B,64,H,W]
    float* tA  = ws + sizeN;
    float* tB  = ws + 2 * sizeN;
    float* wt1 = ws + 3 * sizeN;     // 16*64*64
    float* wt2 = wt1 + 16 * 64 * 64;
    float* n1  = wt2 + 16 * 64 * 64;
    float* n2  = n1 + 64;
    float* dotv = n2 + 64;
    float* attn = dotv + 1024;
    float* tC  = out;                // first sizeN of d_out as scratch (dead
                                     // before the final conv writes d_out)

    const dim3 blk(256);
    const dim3 grid64(256, 8, BB);    // spatial tiles, 64/8 co-groups, batch
    const dim3 grid128(256, 16, BB);  // for COUT=128
    const int w3 = MIDC * MIDC * 9;   // one branch-layer weight block

    // x0 = relu(conv(x, pre))
    conv3x3_kernel<128, 8, 128><<<grid64, blk, 0, stream>>>(
        x, x, pre_w, pre_b, nullptr, x0, 64);

    // branch 1: tA = relu(c1_2(relu(c1_1(relu(c1_0(x0)))))) + x0
    conv3x3_kernel<64, 8, 64><<<grid64, blk, 0, stream>>>(
        x0, x0, c1_w + 0 * w3, c1_b + 0 * MIDC, nullptr, tA, 64);
    conv3x3_kernel<64, 8, 64><<<grid64, blk, 0, stream>>>(
        tA, tA, c1_w + 1 * w3, c1_b + 1 * MIDC, nullptr, tB, 64);
    conv3x3_kernel<64, 8, 64><<<grid64, blk, 0, stream>>>(
        tB, tB, c1_w + 2 * w3, c1_b + 2 * MIDC, x0, tA, 64);

    // branch 2 -> tB (uses d_out scratch as ping buffer)
    conv3x3_kernel<64, 8, 64><<<grid64, blk, 0, stream>>>(
        x0, x0, c2_w + 0 * w3, c2_b + 0 * MIDC, nullptr, tB, 64);
    conv3x3_kernel<64, 8, 64><<<grid64, blk, 0, stream>>>(
        tB, tB, c2_w + 1 * w3, c2_b + 1 * MIDC, nullptr, tC, 64);
    conv3x3_kernel<64, 8, 64><<<grid64, blk, 0, stream>>>(
        tC, tC, c2_w + 2 * w3, c2_b + 2 * MIDC, x0, tB, 64);

    // transpose per-patch weights
    transpose_pw_kernel<<<256, 256, 0, stream>>>(p1_w, wt1);
    transpose_pw_kernel<<<256, 256, 0, stream>>>(p2_w, wt2);

    // per-patch 1x1 convs: x1p -> tC, x2p -> tA
    const dim3 pgrid(256, 4, BB);
    patch1x1_kernel<<<pgrid, blk, 0, stream>>>(tA, wt1, p1_b, tC);
    patch1x1_kernel<<<pgrid, blk, 0, stream>>>(tB, wt2, p2_b, tA);

    // norms + pairwise dots + attention
    patch_norm_kernel<<<BB * PP, blk, 0, stream>>>(tC, n1);
    patch_norm_kernel<<<BB * PP, blk, 0, stream>>>(tA, n2);
    patch_dot_kernel<<<BB * PP * PP, blk, 0, stream>>>(tC, tA, dotv);
    attn_kernel<<<1, 1024, 0, stream>>>(n1, n2, dotv, attn);

    // attnout -> tB
    const dim3 cgrid(256, 64, BB);
    combine_kernel<<<cgrid, blk, 0, stream>>>(attn, tA, tB);

    // final: out = relu(conv(concat[attnout, x0], fin)) + x
    conv3x3_kernel<128, 8, 64><<<grid128, blk, 0, stream>>>(
        tB, x0, fin_w, fin_b, x, out, 128);
}

// Round 2
// 2595.081 us; speedup vs baseline: 4.0601x; 4.0601x over previous
//
#include <hip/hip_runtime.h>
#include <hip/hip_bf16.h>

#define BB   4
#define HH   256
#define WW   256
#define INCH 128
#define MIDC 64
#define NPAT 4
#define PP   16
#define PS   64

typedef __bf16 bf16x8 __attribute__((ext_vector_type(8)));
typedef float f32x4 __attribute__((ext_vector_type(4)));
typedef unsigned short ushort_t;

__device__ inline ushort_t f2bf(float f) {
    unsigned u = __float_as_uint(f);
    unsigned r = (u + 0x7FFFu + ((u >> 16) & 1u)) >> 16;
    return (ushort_t)r;
}
__device__ inline float bf2f(ushort_t h) {
    return __uint_as_float(((unsigned)h) << 16);
}

// ---------------------------------------------------------------------------
// weight prep: [COUT][CIN][3][3] fp32 -> [9][COUT][CIN] bf16
// ---------------------------------------------------------------------------
__global__ __launch_bounds__(256) void prep_w_kernel(
    const float* __restrict__ w, ushort_t* __restrict__ wt, int COUT, int CIN)
{
    int idx = blockIdx.x * 256 + threadIdx.x;
    int n = COUT * CIN * 9;
    if (idx >= n) return;
    int tap = idx % 9;
    int ci  = (idx / 9) % CIN;
    int co  = idx / (9 * CIN);
    wt[((size_t)tap * COUT + co) * CIN + ci] = f2bf(w[idx]);
}

// ---------------------------------------------------------------------------
// MFMA implicit-GEMM 3x3 conv, bf16 in, fp32 accumulate.
// Block 256 thr / 4 waves; out tile 64co x (64x x 4y) pixels.
// Wave w: co [cog+(w&1)*32, +32), rows [(w>>1)*2, +2).
// Input: channels [0,CSPLIT) from inA, rest from inB (concat fusion).
// INF32: inputs are fp32 (converted during staging); else bf16 bits.
// Residual (fp32 resf or bf16 resb) added AFTER relu.
// ---------------------------------------------------------------------------
template<int CIN, int CSPLIT, bool INF32>
__global__ __launch_bounds__(256) void mconv3x3_kernel(
    const void* __restrict__ inA, const void* __restrict__ inB,
    const ushort_t* __restrict__ wgtT,   // [9][COUT][CIN] bf16
    const float* __restrict__ bias,      // [COUT]
    const float* __restrict__ resf,      // nullable fp32 residual
    const ushort_t* __restrict__ resb,   // nullable bf16 residual
    float* __restrict__ outF,            // nullable
    ushort_t* __restrict__ outB,         // nullable
    int COUT)
{
    __shared__ ushort_t sm[6 * 68 * 32];   // [row][x][ci] bf16

    const int t  = threadIdx.x;
    const int bx = blockIdx.x;             // 64 y-tiles x 4 x-tiles
    const int y0 = (bx >> 2) * 4;
    const int x0 = (bx & 3) * 64;
    const int cog = blockIdx.y * 64;
    const int b  = blockIdx.z;

    const int l     = t & 63;
    const int w     = t >> 6;
    const int lan15 = l & 15;
    const int k8    = (l >> 4) * 8;
    const int co0   = cog + (w & 1) * 32;
    const int wrow0 = (w >> 1) * 2;

    f32x4 acc[2][8];
#pragma unroll
    for (int mt = 0; mt < 2; ++mt)
#pragma unroll
        for (int nt = 0; nt < 8; ++nt) acc[mt][nt] = (f32x4)0.f;

    for (int cb = 0; cb < CIN; cb += 32) {
        __syncthreads();
        // stage 32-channel slab with halo: rows y0-1..y0+4, x = x0-1..x0+66
        for (int idx = t; idx < 4 * 6 * 68; idx += 256) {
            int ciq = idx / 408;
            int rem = idx - ciq * 408;
            int row = rem / 68;
            int xl  = rem - row * 68;
            int gy  = y0 + row - 1;
            int gx  = x0 + xl - 1;
            int c0  = cb + ciq * 8;
            bool ok = ((unsigned)gy < (unsigned)HH) && ((unsigned)gx < (unsigned)WW);

            const bool useA = (c0 < CSPLIT);
            const int  chan = useA ? c0 : (c0 - CSPLIT);
            const int  nch  = useA ? CSPLIT : (CIN - CSPLIT);
            const size_t base = ((size_t)(b * nch + chan) * HH + gy) * WW + gx;

            ushort_t u[8];
            if (INF32) {
                const float* src = (const float*)(useA ? inA : inB) + base;
#pragma unroll
                for (int j = 0; j < 8; ++j)
                    u[j] = ok ? f2bf(src[(size_t)j * HH * WW]) : (ushort_t)0;
            } else {
                const ushort_t* src = (const ushort_t*)(useA ? inA : inB) + base;
#pragma unroll
                for (int j = 0; j < 8; ++j)
                    u[j] = ok ? src[(size_t)j * HH * WW] : (ushort_t)0;
            }
            uint4 pk;
            pk.x = (unsigned)u[0] | ((unsigned)u[1] << 16);
            pk.y = (unsigned)u[2] | ((unsigned)u[3] << 16);
            pk.z = (unsigned)u[4] | ((unsigned)u[5] << 16);
            pk.w = (unsigned)u[6] | ((unsigned)u[7] << 16);
            *(uint4*)&sm[(row * 68 + xl) * 32 + ciq * 8] = pk;
        }
        __syncthreads();

        // preload A fragments: 2 M-tiles x 9 taps
        uint4 af[2][9];
#pragma unroll
        for (int mt = 0; mt < 2; ++mt)
#pragma unroll
            for (int tap = 0; tap < 9; ++tap)
                af[mt][tap] = *(const uint4*)(wgtT +
                    ((size_t)(tap * COUT + co0 + mt * 16 + lan15)) * CIN + cb + k8);

#pragma unroll
        for (int dy = 0; dy < 3; ++dy) {
#pragma unroll
            for (int dx = 0; dx < 3; ++dx) {
                const int tap = dy * 3 + dx;
#pragma unroll
                for (int nt = 0; nt < 8; ++nt) {
                    const int r  = wrow0 + (nt >> 2) + dy;
                    const int xc = (nt & 3) * 16 + lan15 + dx;
                    uint4 bv = *(const uint4*)&sm[(r * 68 + xc) * 32 + k8];
                    acc[0][nt] = __builtin_amdgcn_mfma_f32_16x16x32_bf16(
                        __builtin_bit_cast(bf16x8, af[0][tap]),
                        __builtin_bit_cast(bf16x8, bv), acc[0][nt], 0, 0, 0);
                    acc[1][nt] = __builtin_amdgcn_mfma_f32_16x16x32_bf16(
                        __builtin_bit_cast(bf16x8, af[1][tap]),
                        __builtin_bit_cast(bf16x8, bv), acc[1][nt], 0, 0, 0);
                }
            }
        }
    }

    // epilogue: bias, relu, residual, stores
#pragma unroll
    for (int mt = 0; mt < 2; ++mt) {
#pragma unroll
        for (int nt = 0; nt < 8; ++nt) {
            const int y = y0 + wrow0 + (nt >> 2);
            const int x = x0 + (nt & 3) * 16 + lan15;
#pragma unroll
            for (int r = 0; r < 4; ++r) {
                const int co = co0 + mt * 16 + (l >> 4) * 4 + r;
                float v = acc[mt][nt][r] + bias[co];
                v = fmaxf(v, 0.f);
                const size_t oi = ((size_t)(b * COUT + co) * HH + y) * WW + x;
                if (resf) v += resf[oi];
                else if (resb) v += bf2f(resb[oi]);
                if (outF) outF[oi] = v;
                if (outB) outB[oi] = f2bf(v);
            }
        }
    }
}

// ---------------------------------------------------------------------------
// transpose per-patch 1x1 weights [p][d][c] -> [p][c][d]
// ---------------------------------------------------------------------------
__global__ __launch_bounds__(256) void transpose_pw_kernel(
    const float* __restrict__ w, float* __restrict__ wt)
{
    int idx = blockIdx.x * 256 + threadIdx.x;    // 65536
    int p = idx >> 12, d = (idx >> 6) & 63, c = idx & 63;
    wt[((size_t)(p * 64 + c)) * 64 + d] = w[idx];
}

// ---------------------------------------------------------------------------
// per-patch 1x1 conv (fp32)
// ---------------------------------------------------------------------------
__global__ __launch_bounds__(256) void patch1x1_kernel(
    const float* __restrict__ in, const float* __restrict__ wt,
    const float* __restrict__ bias, float* __restrict__ out)
{
    const int tile = blockIdx.x;
    const int y0 = (tile >> 2) * 4;
    const int x0 = (tile & 3) * 64;
    const int dg = blockIdx.y * 16;
    const int b  = blockIdx.z;
    const int t  = threadIdx.x;
    const int lx = t & 63, ly = t >> 6;
    const int y = y0 + ly, x = x0 + lx;
    const int p = (y >> 6) * NPAT + (x >> 6);

    float acc[16];
#pragma unroll
    for (int d = 0; d < 16; ++d) acc[d] = bias[p * 64 + dg + d];

    const float* wp = wt + (size_t)(p * 64) * 64 + dg;
    const float* ip = in + ((size_t)(b * 64) * HH + y) * WW + x;
    for (int c = 0; c < 64; ++c) {
        float v = ip[(size_t)c * HH * WW];
        const float* wc = wp + c * 64;
#pragma unroll
        for (int d = 0; d < 16; ++d) acc[d] = fmaf(v, wc[d], acc[d]);
    }
#pragma unroll
    for (int d = 0; d < 16; ++d)
        out[((size_t)(b * 64 + dg + d) * HH + y) * WW + x] = acc[d];
}

// ---------------------------------------------------------------------------
// per-patch squared norm
// ---------------------------------------------------------------------------
__global__ __launch_bounds__(256) void patch_norm_kernel(
    const float* __restrict__ f, float* __restrict__ outN)
{
    const int bp = blockIdx.x;
    const int b = bp >> 4, p = bp & 15;
    const int py = (p >> 2) * PS, px = (p & 3) * PS;
    const float* base = f + (size_t)(b * 64) * HH * WW;
    float s = 0.f;
    for (int idx = threadIdx.x; idx < 64 * PS * PS; idx += 256) {
        int c = idx >> 12, rem = idx & 4095;
        int i = rem >> 6, j = rem & 63;
        float v = base[((size_t)c * HH + py + i) * WW + px + j];
        s = fmaf(v, v, s);
    }
    __shared__ float red[256];
    red[threadIdx.x] = s; __syncthreads();
    for (int off = 128; off > 0; off >>= 1) {
        if (threadIdx.x < off) red[threadIdx.x] += red[threadIdx.x + off];
        __syncthreads();
    }
    if (threadIdx.x == 0) outN[bp] = red[0];
}

// ---------------------------------------------------------------------------
// pairwise patch dot products
// ---------------------------------------------------------------------------
__global__ __launch_bounds__(256) void patch_dot_kernel(
    const float* __restrict__ f1, const float* __restrict__ f2,
    float* __restrict__ dotv)
{
    const int id = blockIdx.x;
    const int b = id >> 8, p = (id >> 4) & 15, q = id & 15;
    const int py = (p >> 2) * PS, px = (p & 3) * PS;
    const int qy = (q >> 2) * PS, qx = (q & 3) * PS;
    const float* b1 = f1 + (size_t)(b * 64) * HH * WW;
    const float* b2 = f2 + (size_t)(b * 64) * HH * WW;
    float s = 0.f;
    for (int idx = threadIdx.x; idx < 64 * PS * PS; idx += 256) {
        int c = idx >> 12, rem = idx & 4095;
        int i = rem >> 6, j = rem & 63;
        s = fmaf(b1[((size_t)c * HH + py + i) * WW + px + j],
                 b2[((size_t)c * HH + qy + i) * WW + qx + j], s);
    }
    __shared__ float red[256];
    red[threadIdx.x] = s; __syncthreads();
    for (int off = 128; off > 0; off >>= 1) {
        if (threadIdx.x < off) red[threadIdx.x] += red[threadIdx.x + off];
        __syncthreads();
    }
    if (threadIdx.x == 0) dotv[id] = red[0];
}

// ---------------------------------------------------------------------------
// attention weights: d = n1+n2-2dot, diag=1e8, attn = softmax(exp(-d))
// ---------------------------------------------------------------------------
__global__ __launch_bounds__(1024) void attn_kernel(
    const float* __restrict__ n1, const float* __restrict__ n2,
    const float* __restrict__ dotv, float* __restrict__ attn)
{
    __shared__ float tv[1024];
    int t = threadIdx.x;
    int b = t >> 8, p = (t >> 4) & 15, q = t & 15;
    float d = n1[b * 16 + p] + n2[b * 16 + q] - 2.f * dotv[t];
    if (p == q) d = 1e8f;
    float e = expf(-d);
    tv[t] = e;
    __syncthreads();
    const float* row = &tv[(t >> 4) << 4];
    float m = row[0];
#pragma unroll
    for (int j = 1; j < 16; ++j) m = fmaxf(m, row[j]);
    float ssum = 0.f;
#pragma unroll
    for (int j = 0; j < 16; ++j) ssum += expf(row[j] - m);
    attn[t] = expf(e - m) / ssum;
}

// ---------------------------------------------------------------------------
// attention combine -> bf16 output (feeds final conv)
// ---------------------------------------------------------------------------
__global__ __launch_bounds__(256) void combine_kernel(
    const float* __restrict__ attn, const float* __restrict__ x2p,
    ushort_t* __restrict__ outA)
{
    const int tile = blockIdx.x;
    const int y0 = (tile >> 2) * 4;
    const int x0 = (tile & 3) * 64;
    const int c = blockIdx.y, b = blockIdx.z;
    const int t = threadIdx.x;
    const int lx = t & 63, ly = t >> 6;
    const int y = y0 + ly, x = x0 + lx;
    const int p = (y >> 6) * NPAT + (x >> 6);
    const int i = y & 63, j = x & 63;
    const float* arow = attn + (size_t)(b * 16 + p) * 16;
    const float* base = x2p + (size_t)(b * 64 + c) * HH * WW;
    float s = 0.f;
#pragma unroll
    for (int q = 0; q < 16; ++q)
        s = fmaf(arow[q], base[(size_t)((q >> 2) * PS + i) * WW + (q & 3) * PS + j], s);
    outA[((size_t)(b * 64 + c) * HH + y) * WW + x] = f2bf(s);
}

// ---------------------------------------------------------------------------
extern "C" void kernel_launch(void* const* d_in, const int* in_sizes, int n_in,
                              void* d_out, int out_size, void* d_ws, size_t ws_size,
                              hipStream_t stream)
{
    const float* x     = (const float*)d_in[0];
    const float* pre_w = (const float*)d_in[1];
    const float* pre_b = (const float*)d_in[2];
    const float* c1_w  = (const float*)d_in[3];
    const float* c1_b  = (const float*)d_in[4];
    const float* c2_w  = (const float*)d_in[5];
    const float* c2_b  = (const float*)d_in[6];
    const float* p1_w  = (const float*)d_in[7];
    const float* p1_b  = (const float*)d_in[8];
    const float* p2_w  = (const float*)d_in[9];
    const float* p2_b  = (const float*)d_in[10];
    const float* fin_w = (const float*)d_in[11];
    const float* fin_b = (const float*)d_in[12];

    float* out = (float*)d_out;
    float* ws  = (float*)d_ws;

    const size_t sizeN = (size_t)BB * MIDC * HH * WW;   // 16,777,216

    // fp32 slots: F1 in ws; F2/F3 borrow d_out (dead before final conv)
    float*    F1  = ws;             // x1f, later x2p
    float*    F2  = out;            // x2f
    float*    F3  = out + sizeN;    // x1p
    ushort_t* x0b = (ushort_t*)(ws + sizeN);
    ushort_t* t1b = x0b + sizeN;
    ushort_t* t2b = t1b + sizeN;
    ushort_t* cmb = t2b + sizeN;
    ushort_t* wpPre = cmb + sizeN;            // 9*64*128
    ushort_t* wpC1  = wpPre + 9 * 64 * 128;   // 3 x 9*64*64
    ushort_t* wpC2  = wpC1 + 3 * 9 * 64 * 64;
    ushort_t* wpFin = wpC2 + 3 * 9 * 64 * 64; // 9*128*128
    float* wt1  = (float*)(wpFin + 9 * 128 * 128);
    float* wt2  = wt1 + 16 * 64 * 64;
    float* n1   = wt2 + 16 * 64 * 64;
    float* n2   = n1 + 64;
    float* dotv = n2 + 64;
    float* attn = dotv + 1024;

    const dim3 blk(256);
    const int w3 = MIDC * MIDC * 9;

    // weight prep
    prep_w_kernel<<<(64 * 128 * 9 + 255) / 256, blk, 0, stream>>>(pre_w, wpPre, 64, 128);
    for (int i = 0; i < 3; ++i) {
        prep_w_kernel<<<(64 * 64 * 9 + 255) / 256, blk, 0, stream>>>(
            c1_w + (size_t)i * w3, wpC1 + (size_t)i * 9 * 64 * 64, 64, 64);
        prep_w_kernel<<<(64 * 64 * 9 + 255) / 256, blk, 0, stream>>>(
            c2_w + (size_t)i * w3, wpC2 + (size_t)i * 9 * 64 * 64, 64, 64);
    }
    prep_w_kernel<<<(128 * 128 * 9 + 255) / 256, blk, 0, stream>>>(fin_w, wpFin, 128, 128);
    transpose_pw_kernel<<<256, blk, 0, stream>>>(p1_w, wt1);
    transpose_pw_kernel<<<256, blk, 0, stream>>>(p2_w, wt2);

    const dim3 g64(256, 1, BB);
    const dim3 g128(256, 2, BB);

    // pre conv: x (fp32) -> x0b (bf16)
    mconv3x3_kernel<128, 128, true><<<g64, blk, 0, stream>>>(
        x, x, wpPre, pre_b, nullptr, nullptr, nullptr, x0b, 64);

    // branch 1: x0b -> t1b -> t2b -> F1 (x1 fp32, +x0 residual)
    mconv3x3_kernel<64, 64, false><<<g64, blk, 0, stream>>>(
        x0b, x0b, wpC1, c1_b, nullptr, nullptr, nullptr, t1b, 64);
    mconv3x3_kernel<64, 64, false><<<g64, blk, 0, stream>>>(
        t1b, t1b, wpC1 + (size_t)1 * 9 * 64 * 64, c1_b + 64, nullptr, nullptr, nullptr, t2b, 64);
    mconv3x3_kernel<64, 64, false><<<g64, blk, 0, stream>>>(
        t2b, t2b, wpC1 + (size_t)2 * 9 * 64 * 64, c1_b + 128, nullptr, x0b, F1, nullptr, 64);

    // branch 2: x0b -> t1b -> t2b -> F2 (x2 fp32, +x0 residual)
    mconv3x3_kernel<64, 64, false><<<g64, blk, 0, stream>>>(
        x0b, x0b, wpC2, c2_b, nullptr, nullptr, nullptr, t1b, 64);
    mconv3x3_kernel<64, 64, false><<<g64, blk, 0, stream>>>(
        t1b, t1b, wpC2 + (size_t)1 * 9 * 64 * 64, c2_b + 64, nullptr, nullptr, nullptr, t2b, 64);
    mconv3x3_kernel<64, 64, false><<<g64, blk, 0, stream>>>(
        t2b, t2b, wpC2 + (size_t)2 * 9 * 64 * 64, c2_b + 128, nullptr, x0b, F2, nullptr, 64);

    // per-patch 1x1: x1(F1) -> x1p(F3);  x2(F2) -> x2p(F1)
    const dim3 pgrid(256, 4, BB);
    patch1x1_kernel<<<pgrid, blk, 0, stream>>>(F1, wt1, p1_b, F3);
    patch1x1_kernel<<<pgrid, blk, 0, stream>>>(F2, wt2, p2_b, F1);

    // norms, dots, attention
    patch_norm_kernel<<<BB * PP, blk, 0, stream>>>(F3, n1);
    patch_norm_kernel<<<BB * PP, blk, 0, stream>>>(F1, n2);
    patch_dot_kernel<<<BB * PP * PP, blk, 0, stream>>>(F3, F1, dotv);
    attn_kernel<<<1, 1024, 0, stream>>>(n1, n2, dotv, attn);

    // combine: attn x x2p(F1) -> cmb (bf16)
    const dim3 cgrid(256, 64, BB);
    combine_kernel<<<cgrid, blk, 0, stream>>>(attn, F1, cmb);

    // final conv: concat[cmb, x0b] (CSPLIT=64) -> d_out (fp32, +x residual)
    mconv3x3_kernel<128, 64, false><<<g128, blk, 0, stream>>>(
        cmb, x0b, wpFin, fin_b, x, nullptr, out, nullptr, 128);
}

// Round 3
// 678.043 us; speedup vs baseline: 15.5393x; 3.8273x over previous
//
#include <hip/hip_runtime.h>
#include <hip/hip_bf16.h>

#define BB   4
#define HH   256
#define WW   256
#define INCH 128
#define MIDC 64
#define NPAT 4
#define PP   16
#define PS   64

typedef __bf16 bf16x8 __attribute__((ext_vector_type(8)));
typedef float f32x4 __attribute__((ext_vector_type(4)));
typedef unsigned short ushort_t;

__device__ inline ushort_t f2bf(float f) {
    unsigned u = __float_as_uint(f);
    unsigned r = (u + 0x7FFFu + ((u >> 16) & 1u)) >> 16;
    return (ushort_t)r;
}
__device__ inline float bf2f(ushort_t h) {
    return __uint_as_float(((unsigned)h) << 16);
}
__device__ inline f32x4 mfma16(uint4 a, uint4 b, f32x4 c) {
    return __builtin_amdgcn_mfma_f32_16x16x32_bf16(
        __builtin_bit_cast(bf16x8, a), __builtin_bit_cast(bf16x8, b), c, 0, 0, 0);
}

// ---------------------------------------------------------------------------
// weight prep: [COUT][CIN][3][3] fp32 -> [9][COUT][CIN] bf16
// ---------------------------------------------------------------------------
__global__ __launch_bounds__(256) void prep_w_kernel(
    const float* __restrict__ w, ushort_t* __restrict__ wt, int COUT, int CIN)
{
    int idx = blockIdx.x * 256 + threadIdx.x;
    int n = COUT * CIN * 9;
    if (idx >= n) return;
    int tap = idx % 9;
    int ci  = (idx / 9) % CIN;
    int co  = idx / (9 * CIN);
    wt[((size_t)tap * COUT + co) * CIN + ci] = f2bf(w[idx]);
}

// elementwise fp32 -> bf16 (per-patch 1x1 weights, layout [p][d][c] kept)
__global__ __launch_bounds__(256) void cvt_bf16_kernel(
    const float* __restrict__ w, ushort_t* __restrict__ o, int n)
{
    int idx = blockIdx.x * 256 + threadIdx.x;
    if (idx < n) o[idx] = f2bf(w[idx]);
}

// ---------------------------------------------------------------------------
// x fp32 NCHW -> bf16 NHWC  (LDS tile transpose: 64 px x 128 ch per block)
// ---------------------------------------------------------------------------
__global__ __launch_bounds__(256) void x_to_nhwc_kernel(
    const float* __restrict__ x, ushort_t* __restrict__ xh)
{
    __shared__ ushort_t sm[64 * 136];
    const int t = threadIdx.x;
    const int bx = blockIdx.x;             // 4096: b*1024 + pxtile
    const int b = bx >> 10;
    const int pxbase = (bx & 1023) * 64;
#pragma unroll
    for (int i = 0; i < 32; ++i) {
        int idx = i * 256 + t;             // [128 c][64 px]
        int c = idx >> 6, pxl = idx & 63;
        sm[pxl * 136 + c] = f2bf(x[((size_t)(b * 128 + c)) * 65536 + pxbase + pxl]);
    }
    __syncthreads();
#pragma unroll
    for (int i = 0; i < 4; ++i) {
        int idx = i * 256 + t;             // [64 px][16 quads]
        int pxl = idx >> 4, q = idx & 15;
        uint4 v = *(const uint4*)&sm[pxl * 136 + q * 8];
        *(uint4*)(xh + ((size_t)b * 65536 + pxbase + pxl) * 128 + q * 8) = v;
    }
}

// ---------------------------------------------------------------------------
// staging helper: 32-ch slab (with halo) of NHWC bf16 into regs
// ---------------------------------------------------------------------------
template<int CIN, int CSPLIT>
__device__ inline void stage_loads(const ushort_t* inA, const ushort_t* inB,
                                   int b, int y0, int x0, int t, int cb,
                                   uint4 (&stg)[7])
{
#pragma unroll
    for (int i = 0; i < 7; ++i) {
        int idx = i * 256 + t;             // [408 px][4 quads], 1632 total
        int pxl = idx >> 2, quad = idx & 3;
        int row = pxl / 68, xl = pxl - row * 68;
        int gy = y0 + row - 1, gx = x0 + xl - 1;
        bool ok = (idx < 1632) && ((unsigned)gy < 256u) && ((unsigned)gx < 256u);
        int c0 = cb + quad * 8;
        const ushort_t* src; int stride, ch;
        if ((CSPLIT == CIN) || (c0 < CSPLIT)) { src = inA; stride = CSPLIT; ch = c0; }
        else { src = inB; stride = CIN - CSPLIT; ch = c0 - CSPLIT; }
        uint4 v = make_uint4(0u, 0u, 0u, 0u);
        if (ok) v = *(const uint4*)(src + ((size_t)((b * 256 + gy) * 256 + gx)) * stride + ch);
        stg[i] = v;
    }
}

// ---------------------------------------------------------------------------
// MFMA implicit-GEMM 3x3 conv, bf16 NHWC in, fp32 accumulate.
// Block 256 thr / 4 waves; out tile 64co x (64x x 4y) px.
// OMODE: 0 = bf16 NHWC out; 1 = bf16 NHWC out + bf16 NHWC residual;
//        2 = fp32 NCHW out + fp32 NCHW residual.
// ---------------------------------------------------------------------------
template<int CIN, int CSPLIT, int OMODE>
__global__ __launch_bounds__(256) void mconv3x3(
    const ushort_t* __restrict__ inA, const ushort_t* __restrict__ inB,
    const ushort_t* __restrict__ wgtT,   // [9][COUT][CIN] bf16
    const float* __restrict__ bias,
    const void* __restrict__ res,
    void* __restrict__ out,
    int COUT)
{
    constexpr int NCH = CIN / 32;
    __shared__ ushort_t sm[6 * 68 * 40];   // [px_lin][40] pad: 80 B stride

    const int t = threadIdx.x;
    const int bx = blockIdx.x;             // 64 y-tiles x 4 x-tiles
    const int y0 = (bx >> 2) * 4;
    const int x0 = (bx & 3) * 64;
    const int cog = blockIdx.y * 64;
    const int b = blockIdx.z;
    const int l = t & 63;
    const int w = t >> 6;
    const int lan15 = l & 15;
    const int k8 = (l >> 4) * 8;
    const int co0 = cog + (w & 1) * 32;
    const int wrow0 = (w >> 1) * 2;

    f32x4 acc[2][8];
#pragma unroll
    for (int mt = 0; mt < 2; ++mt)
#pragma unroll
        for (int nt = 0; nt < 8; ++nt) acc[mt][nt] = (f32x4)0.f;

    uint4 stg[7];
    stage_loads<CIN, CSPLIT>(inA, inB, b, y0, x0, t, 0, stg);

    for (int cc = 0; cc < NCH; ++cc) {
        __syncthreads();                   // all waves done reading prev slab
#pragma unroll
        for (int i = 0; i < 7; ++i) {
            int idx = i * 256 + t;
            if (idx < 1632) {
                int pxl = idx >> 2, quad = idx & 3;
                *(uint4*)&sm[pxl * 40 + quad * 8] = stg[i];
            }
        }
        __syncthreads();                   // slab ready
        if (cc + 1 < NCH)                  // prefetch next slab (overlaps MFMA)
            stage_loads<CIN, CSPLIT>(inA, inB, b, y0, x0, t, (cc + 1) * 32, stg);

        const int cb = cc * 32;
        uint4 af[2][9];
#pragma unroll
        for (int mt = 0; mt < 2; ++mt)
#pragma unroll
            for (int tap = 0; tap < 9; ++tap)
                af[mt][tap] = *(const uint4*)(wgtT +
                    ((size_t)tap * COUT + co0 + mt * 16 + lan15) * CIN + cb + k8);

#pragma unroll
        for (int rr = 0; rr < 4; ++rr) {
            const int r = wrow0 + rr;
#pragma unroll
            for (int col = 0; col < 4; ++col) {
#pragma unroll
                for (int dx = 0; dx < 3; ++dx) {
                    const int xc = col * 16 + lan15 + dx;
                    uint4 bv = *(const uint4*)&sm[(r * 68 + xc) * 40 + k8];
#pragma unroll
                    for (int drow = 0; drow < 2; ++drow) {
                        const int dy = rr - drow;
                        if (dy >= 0 && dy < 3) {
                            const int tap = dy * 3 + dx;
                            const int nt = drow * 4 + col;
                            acc[0][nt] = mfma16(af[0][tap], bv, acc[0][nt]);
                            acc[1][nt] = mfma16(af[1][tap], bv, acc[1][nt]);
                        }
                    }
                }
            }
        }
    }

    // epilogue
#pragma unroll
    for (int mt = 0; mt < 2; ++mt) {
#pragma unroll
        for (int nt = 0; nt < 8; ++nt) {
            const int y = y0 + wrow0 + (nt >> 2);
            const int x = x0 + (nt & 3) * 16 + lan15;
            const int codr = co0 + mt * 16 + (l >> 4) * 4;
            float v[4];
#pragma unroll
            for (int r = 0; r < 4; ++r)
                v[r] = fmaxf(acc[mt][nt][r] + bias[codr + r], 0.f);
            if constexpr (OMODE == 2) {
                const float* rf = (const float*)res;
                float* of = (float*)out;
#pragma unroll
                for (int r = 0; r < 4; ++r) {
                    size_t oi = ((size_t)(b * COUT + codr + r) * 256 + y) * 256 + x;
                    of[oi] = v[r] + rf[oi];
                }
            } else {
                const size_t pix = (size_t)(b * 256 + y) * 256 + x;
                if constexpr (OMODE == 1) {
                    const ushort_t* rp = (const ushort_t*)res + pix * 64 + codr;
#pragma unroll
                    for (int r = 0; r < 4; ++r) v[r] += bf2f(rp[r]);
                }
                uint2 pk;
                pk.x = (unsigned)f2bf(v[0]) | ((unsigned)f2bf(v[1]) << 16);
                pk.y = (unsigned)f2bf(v[2]) | ((unsigned)f2bf(v[3]) << 16);
                *(uint2*)((ushort_t*)out + pix * COUT + codr) = pk;
            }
        }
    }
}

// ---------------------------------------------------------------------------
// per-patch 1x1 conv via MFMA: in bf16 NHWC -> out bf16 NHWC (+bias),
// fused squared-norm atomics (fp32, pre-rounding).
// grid (16 px-tiles, B*P); block 256 = 4 waves; tile 64d x 256px; K=64.
// ---------------------------------------------------------------------------
__global__ __launch_bounds__(256) void patch1x1_mfma(
    const ushort_t* __restrict__ in, const ushort_t* __restrict__ pwb, // [p][d][c] bf16
    const float* __restrict__ bias,                                    // [p][d]
    ushort_t* __restrict__ outp, float* __restrict__ nrm)
{
    __shared__ ushort_t smp[256 * 72];
    const int t = threadIdx.x;
    const int bx = blockIdx.x;         // iy0 = bx*4
    const int bp = blockIdx.y;
    const int b = bp >> 4, p = bp & 15;
    const int py = (p >> 2) * 64, px0 = (p & 3) * 64;
    const int l = t & 63, w = t >> 6;
    const int lan15 = l & 15, k8 = (l >> 4) * 8;

#pragma unroll
    for (int i = 0; i < 8; ++i) {
        int idx = i * 256 + t;         // [256 px][8 quads]
        int px = idx >> 3, q = idx & 7;
        int y = py + bx * 4 + (px >> 6), x = px0 + (px & 63);
        uint4 v = *(const uint4*)(in + ((size_t)(b * 256 + y) * 256 + x) * 64 + q * 8);
        *(uint4*)&smp[px * 72 + q * 8] = v;
    }
    __syncthreads();

    uint4 af[4][2];
#pragma unroll
    for (int mt = 0; mt < 4; ++mt)
#pragma unroll
        for (int kk = 0; kk < 2; ++kk)
            af[mt][kk] = *(const uint4*)(pwb + (size_t)p * 4096 +
                                         (mt * 16 + lan15) * 64 + kk * 32 + k8);

    f32x4 acc[4][4];
#pragma unroll
    for (int mt = 0; mt < 4; ++mt)
#pragma unroll
        for (int j = 0; j < 4; ++j) acc[mt][j] = (f32x4)0.f;

#pragma unroll
    for (int kk = 0; kk < 2; ++kk)
#pragma unroll
        for (int j = 0; j < 4; ++j) {
            int px = (w * 4 + j) * 16 + lan15;
            uint4 bv = *(const uint4*)&smp[px * 72 + kk * 32 + k8];
#pragma unroll
            for (int mt = 0; mt < 4; ++mt)
                acc[mt][j] = mfma16(af[mt][kk], bv, acc[mt][j]);
        }

    float nsum = 0.f;
#pragma unroll
    for (int mt = 0; mt < 4; ++mt)
#pragma unroll
        for (int j = 0; j < 4; ++j) {
            int px = (w * 4 + j) * 16 + lan15;
            int y = py + bx * 4 + (px >> 6), x = px0 + (px & 63);
            int d0 = mt * 16 + (l >> 4) * 4;
            float v[4];
#pragma unroll
            for (int r = 0; r < 4; ++r) {
                v[r] = acc[mt][j][r] + bias[p * 64 + d0 + r];
                nsum = fmaf(v[r], v[r], nsum);
            }
            uint2 pk;
            pk.x = (unsigned)f2bf(v[0]) | ((unsigned)f2bf(v[1]) << 16);
            pk.y = (unsigned)f2bf(v[2]) | ((unsigned)f2bf(v[3]) << 16);
            *(uint2*)(outp + ((size_t)(b * 256 + y) * 256 + x) * 64 + d0) = pk;
        }

#pragma unroll
    for (int off = 32; off > 0; off >>= 1) nsum += __shfl_down(nsum, off);
    if (l == 0) atomicAdd(&nrm[b * 16 + p], nsum);
}

// ---------------------------------------------------------------------------
// pairwise patch dots via MFMA: dotv[b][p][q] += f1_p . f2_q
// grid (64 k-blocks, B); block 256 = 4 waves; K-chunk = one patch row.
// ---------------------------------------------------------------------------
__global__ __launch_bounds__(256) void patch_dots_mfma(
    const ushort_t* __restrict__ f1, const ushort_t* __restrict__ f2,
    float* __restrict__ dotv)
{
    __shared__ float rbuf[4][64][4];
    const int t = threadIdx.x;
    const int kb = blockIdx.x;         // patch-local row iy
    const int b = blockIdx.y;
    const int l = t & 63, w = t >> 6;
    const int lan15 = l & 15, k8q = (l >> 4) * 8;
    const int p = lan15;               // A row index == B col index
    const int py = (p >> 2) * 64, px0 = (p & 3) * 64;
    const size_t rowbase = ((size_t)(b * 256 + py + kb) * 256 + px0) * 64;

    f32x4 acc = (f32x4)0.f;
    for (int ixl = 0; ixl < 16; ++ixl) {
        const size_t pa = rowbase + (size_t)(w * 16 + ixl) * 64 + k8q;
#pragma unroll
        for (int c0 = 0; c0 < 64; c0 += 32) {
            uint4 av = *(const uint4*)(f1 + pa + c0);
            uint4 bv = *(const uint4*)(f2 + pa + c0);
            acc = mfma16(av, bv, acc);
        }
    }
#pragma unroll
    for (int r = 0; r < 4; ++r) rbuf[w][l][r] = acc[r];
    __syncthreads();
    if (t < 64) {
#pragma unroll
        for (int r = 0; r < 4; ++r) {
            float s = rbuf[0][t][r] + rbuf[1][t][r] + rbuf[2][t][r] + rbuf[3][t][r];
            int pp = (t >> 4) * 4 + r, qq = t & 15;
            atomicAdd(&dotv[b * 256 + pp * 16 + qq], s);
        }
    }
}

// ---------------------------------------------------------------------------
// attention weights: d = n1+n2-2dot, diag=1e8, attn = softmax(exp(-d))
// ---------------------------------------------------------------------------
__global__ __launch_bounds__(1024) void attn_kernel(
    const float* __restrict__ n1, const float* __restrict__ n2,
    const float* __restrict__ dotv, float* __restrict__ attn)
{
    __shared__ float tv[1024];
    int t = threadIdx.x;
    int b = t >> 8, p = (t >> 4) & 15, q = t & 15;
    float d = n1[b * 16 + p] + n2[b * 16 + q] - 2.f * dotv[t];
    if (p == q) d = 1e8f;
    float e = expf(-d);
    tv[t] = e;
    __syncthreads();
    const float* row = &tv[(t >> 4) << 4];
    float m = row[0];
#pragma unroll
    for (int j = 1; j < 16; ++j) m = fmaxf(m, row[j]);
    float ssum = 0.f;
#pragma unroll
    for (int j = 0; j < 16; ++j) ssum += expf(row[j] - m);
    attn[t] = expf(e - m) / ssum;
}

// ---------------------------------------------------------------------------
// combine: cmb[b,px in p][c] = sum_q attn[b,p,q] * x2p[b, q-px][c]  (NHWC bf16)
// ---------------------------------------------------------------------------
__global__ __launch_bounds__(256) void combine_kernel(
    const float* __restrict__ attn, const ushort_t* __restrict__ x2p,
    ushort_t* __restrict__ cmb)
{
    int gid = blockIdx.x * 256 + threadIdx.x;   // B*65536*8
    int cq = gid & 7;
    int pxg = (gid >> 3) & 65535;
    int b = gid >> 19;
    int y = pxg >> 8, x = pxg & 255;
    int p = (y >> 6) * 4 + (x >> 6);
    int i = y & 63, j = x & 63;
    const float* arow = attn + (size_t)(b * 16 + p) * 16;
    float s[8];
#pragma unroll
    for (int k = 0; k < 8; ++k) s[k] = 0.f;
#pragma unroll
    for (int q = 0; q < 16; ++q) {
        float a = arow[q];
        const ushort_t* sp = x2p +
            ((size_t)(b * 256 + (q >> 2) * 64 + i) * 256 + (q & 3) * 64 + j) * 64 + cq * 8;
        uint4 v = *(const uint4*)sp;
        unsigned uu[4] = {v.x, v.y, v.z, v.w};
#pragma unroll
        for (int h = 0; h < 4; ++h) {
            s[h * 2]     = fmaf(a, bf2f((ushort_t)(uu[h] & 0xffffu)), s[h * 2]);
            s[h * 2 + 1] = fmaf(a, bf2f((ushort_t)(uu[h] >> 16)),     s[h * 2 + 1]);
        }
    }
    uint4 o;
    o.x = (unsigned)f2bf(s[0]) | ((unsigned)f2bf(s[1]) << 16);
    o.y = (unsigned)f2bf(s[2]) | ((unsigned)f2bf(s[3]) << 16);
    o.z = (unsigned)f2bf(s[4]) | ((unsigned)f2bf(s[5]) << 16);
    o.w = (unsigned)f2bf(s[6]) | ((unsigned)f2bf(s[7]) << 16);
    *(uint4*)(cmb + ((size_t)b * 65536 + pxg) * 64 + cq * 8) = o;
}

// ---------------------------------------------------------------------------
extern "C" void kernel_launch(void* const* d_in, const int* in_sizes, int n_in,
                              void* d_out, int out_size, void* d_ws, size_t ws_size,
                              hipStream_t stream)
{
    const float* x     = (const float*)d_in[0];
    const float* pre_w = (const float*)d_in[1];
    const float* pre_b = (const float*)d_in[2];
    const float* c1_w  = (const float*)d_in[3];
    const float* c1_b  = (const float*)d_in[4];
    const float* c2_w  = (const float*)d_in[5];
    const float* c2_b  = (const float*)d_in[6];
    const float* p1_w  = (const float*)d_in[7];
    const float* p1_b  = (const float*)d_in[8];
    const float* p2_w  = (const float*)d_in[9];
    const float* p2_b  = (const float*)d_in[10];
    const float* fin_w = (const float*)d_in[11];
    const float* fin_b = (const float*)d_in[12];

    float* out = (float*)d_out;
    ushort_t* wsu = (ushort_t*)d_ws;

    const size_t U = (size_t)BB * 65536 * 64;   // 16,777,216 elems (bf16 plane set)

    // ws layout (ushort units)
    ushort_t* xh   = wsu;              // 2U : x in NHWC bf16 (128 ch); later x1p/x2p
    ushort_t* x0b  = wsu + 2 * U;      // 1U
    ushort_t* t1b  = wsu + 3 * U;      // 1U ; later cmb
    ushort_t* t2b  = wsu + 4 * U;      // 1U
    ushort_t* x1p  = xh;               // reuse (xh dead after pre-conv)
    ushort_t* x2p  = xh + U;
    ushort_t* cmb  = t1b;              // reuse (t1b dead after branch2)

    ushort_t* wpPre = wsu + 5 * U;                 // 9*64*128
    ushort_t* wpC1  = wpPre + 9 * 64 * 128;        // 3 x 9*64*64
    ushort_t* wpC2  = wpC1 + 3 * 9 * 64 * 64;
    ushort_t* wpFin = wpC2 + 3 * 9 * 64 * 64;      // 9*128*128
    ushort_t* pw1b  = wpFin + 9 * 128 * 128;       // 16*64*64
    ushort_t* pw2b  = pw1b + 16 * 64 * 64;
    float* n1   = (float*)(pw2b + 16 * 64 * 64);
    float* n2   = n1 + 64;
    float* dotv = n2 + 64;
    float* attn = dotv + 1024;

    // x1/x2 bf16 borrow d_out (dead before final conv writes)
    ushort_t* x1b = (ushort_t*)d_out;
    ushort_t* x2b = x1b + U;

    const dim3 blk(256);
    const int w3 = MIDC * MIDC * 9;

    // ---- weight prep
    prep_w_kernel<<<(64 * 128 * 9 + 255) / 256, blk, 0, stream>>>(pre_w, wpPre, 64, 128);
    for (int i = 0; i < 3; ++i) {
        prep_w_kernel<<<(36864 + 255) / 256, blk, 0, stream>>>(
            c1_w + (size_t)i * w3, wpC1 + (size_t)i * 36864, 64, 64);
        prep_w_kernel<<<(36864 + 255) / 256, blk, 0, stream>>>(
            c2_w + (size_t)i * w3, wpC2 + (size_t)i * 36864, 64, 64);
    }
    prep_w_kernel<<<(128 * 128 * 9 + 255) / 256, blk, 0, stream>>>(fin_w, wpFin, 128, 128);
    cvt_bf16_kernel<<<256, blk, 0, stream>>>(p1_w, pw1b, 65536);
    cvt_bf16_kernel<<<256, blk, 0, stream>>>(p2_w, pw2b, 65536);

    // zero accumulators (n1, n2, dotv contiguous)
    hipMemsetAsync(n1, 0, (64 + 64 + 1024) * sizeof(float), stream);

    // ---- x -> NHWC bf16
    x_to_nhwc_kernel<<<4096, blk, 0, stream>>>(x, xh);

    const dim3 g64(256, 1, BB);
    const dim3 g128(256, 2, BB);

    // ---- pre conv (128 -> 64)
    mconv3x3<128, 128, 0><<<g64, blk, 0, stream>>>(
        xh, xh, wpPre, pre_b, nullptr, x0b, 64);

    // ---- branch 1
    mconv3x3<64, 64, 0><<<g64, blk, 0, stream>>>(x0b, x0b, wpC1, c1_b, nullptr, t1b, 64);
    mconv3x3<64, 64, 0><<<g64, blk, 0, stream>>>(t1b, t1b, wpC1 + 36864, c1_b + 64, nullptr, t2b, 64);
    mconv3x3<64, 64, 1><<<g64, blk, 0, stream>>>(t2b, t2b, wpC1 + 2 * 36864, c1_b + 128, x0b, x1b, 64);

    // ---- branch 2
    mconv3x3<64, 64, 0><<<g64, blk, 0, stream>>>(x0b, x0b, wpC2, c2_b, nullptr, t1b, 64);
    mconv3x3<64, 64, 0><<<g64, blk, 0, stream>>>(t1b, t1b, wpC2 + 36864, c2_b + 64, nullptr, t2b, 64);
    mconv3x3<64, 64, 1><<<g64, blk, 0, stream>>>(t2b, t2b, wpC2 + 2 * 36864, c2_b + 128, x0b, x2b, 64);

    // ---- per-patch 1x1 (MFMA) + fused norms
    const dim3 pgrid(16, BB * PP);
    patch1x1_mfma<<<pgrid, blk, 0, stream>>>(x1b, pw1b, p1_b, x1p, n1);
    patch1x1_mfma<<<pgrid, blk, 0, stream>>>(x2b, pw2b, p2_b, x2p, n2);

    // ---- pairwise dots (MFMA, split-K atomics)
    const dim3 dgrid(64, BB);
    patch_dots_mfma<<<dgrid, blk, 0, stream>>>(x1p, x2p, dotv);

    // ---- attention
    attn_kernel<<<1, 1024, 0, stream>>>(n1, n2, dotv, attn);

    // ---- combine
    combine_kernel<<<BB * 65536 * 8 / 256, blk, 0, stream>>>(attn, x2p, cmb);

    // ---- final conv: concat[cmb, x0b] -> d_out fp32 NCHW (+x residual)
    mconv3x3<128, 64, 2><<<g128, blk, 0, stream>>>(
        cmb, x0b, wpFin, fin_b, x, out, 128);
}